// Round 6
// baseline (8511.817 us; speedup 1.0000x reference)
//
#include <hip/hip_runtime.h>
#include <hip/hip_bf16.h>

// GRU-imputation scan (B=128,T=128,D=128,H=1024,L=3), f32 in/out.
// Round 6: r5 structure + weight PREFETCH INTO VGPRS overlapped with the
// barrier spin. Weights are loop-invariant; only h depends on the barrier.
// Each wave prefetches its next-phase 16 B-fragments (64 VGPRs) before
// arriving; after the barrier the phase is stage-h -> MFMA(regs x LDS) ->
// epilogue. 4 row groups x 32 blocks, relaxed-atomic group barriers,
// sc0/sc1-coherent h/comp, bf16-packed L2-resident weights.

typedef __hip_bfloat16 bf16;
typedef unsigned int u32;
typedef unsigned short u16;
typedef __attribute__((ext_vector_type(8))) short v8bf;   // 8 x bf16 (16B)
typedef __attribute__((ext_vector_type(4))) float v4f;    // MFMA C/D
typedef __attribute__((ext_vector_type(4))) u32 v4u;

#define SC __HIP_MEMORY_SCOPE_AGENT

__device__ __forceinline__ float bf2f(bf16 v){ return __bfloat162float(v); }
__device__ __forceinline__ bf16 f2bf(float v){ return __float2bfloat16(v); }
__device__ __forceinline__ float sigm(float x){ return 1.f/(1.f + __expf(-x)); }
__device__ __forceinline__ float tanh_(float x){
  float a = fminf(fmaxf(x, -15.f), 15.f);
  float t = __expf(2.f*a);
  return (t-1.f)/(t+1.f);
}
__device__ __forceinline__ v8bf ldv(const bf16* p){ return *reinterpret_cast<const v8bf*>(p); }
__device__ __forceinline__ void vdrain(){ asm volatile("s_waitcnt vmcnt(0)" ::: "memory"); }

// ---- device-coherent (LLC) accesses: bypass L1+L2 via sc0 sc1 ----
__device__ __forceinline__ void ldx4_coh(const bf16* p0, const bf16* p1,
                                         const bf16* p2, const bf16* p3,
                                         v4u& r0, v4u& r1, v4u& r2, v4u& r3){
  asm volatile(
    "global_load_dwordx4 %0, %4, off sc0 sc1\n\t"
    "global_load_dwordx4 %1, %5, off sc0 sc1\n\t"
    "global_load_dwordx4 %2, %6, off sc0 sc1\n\t"
    "global_load_dwordx4 %3, %7, off sc0 sc1\n\t"
    "s_waitcnt vmcnt(0)"
    : "=&v"(r0), "=&v"(r1), "=&v"(r2), "=&v"(r3)
    : "v"(p0), "v"(p1), "v"(p2), "v"(p3)
    : "memory");
}
__device__ __forceinline__ v4u ldx1_coh(const bf16* p){
  v4u r;
  asm volatile("global_load_dwordx4 %0, %1, off sc0 sc1\n\ts_waitcnt vmcnt(0)"
               : "=&v"(r) : "v"(p) : "memory");
  return r;
}
__device__ __forceinline__ void st2_coh(bf16* p, bf16 v){
  u32 vv = (u32)__builtin_bit_cast(u16, v);
  asm volatile("global_store_short %0, %1, off sc0 sc1" :: "v"(p), "v"(vv) : "memory");
}

// ---- per-group barrier: 32 arrivals, relaxed atomics, no cache ops ----
__device__ __forceinline__ void gbar2(u32* ctr, u32* ep, u32 target){
  __syncthreads();
  if (threadIdx.x == 0){
    vdrain();
    u32 a = __hip_atomic_fetch_add(ctr, 1u, __ATOMIC_RELAXED, SC);
    if (a == 31u){
      __hip_atomic_store(ctr, 0u, __ATOMIC_RELAXED, SC);
      vdrain();
      __hip_atomic_fetch_add(ep, 1u, __ATOMIC_RELAXED, SC);
    }
    while (__hip_atomic_load(ep, __ATOMIC_RELAXED, SC) < target){
      __builtin_amdgcn_s_sleep(1);
    }
  }
  __syncthreads();
}

// =================================================================
// Packing kernels (validated rounds 4-5). Fragment unit = 64 lanes x 8 bf16:
//   lane's 8 elems = W[row(j,lane&15)][kk*32 + ((lane>>4)&3)*8 + e]
// =================================================================
__global__ void pack_upper_k(const float* __restrict__ Wih, const float* __restrict__ Whh,
                             bf16* __restrict__ dst){
  int tid = blockIdx.x*256 + threadIdx.x;          // 1,048,576
  int lane = tid & 63;
  int u    = tid >> 6;
  int kk   = u & 31;
  int j    = (u >> 5) & 63;
  int s    = (u >> 11) & 3;
  int l    = u >> 13;
  int n    = j*16 + (lane & 15);
  int k    = kk*32 + ((lane>>4)&3)*8;
  int row  = (s==0) ? n : (s==1 ? 1024+n : 2048+n);
  size_t src = ((size_t)l*3072 + row)*1024 + k;
  size_t o = (size_t)tid*8;
  #pragma unroll
  for (int e=0;e<8;e++){
    float v;
    if (s < 2)      v = Wih[src+e] + Whh[src+e];
    else if (s==2)  v = Wih[src+e];
    else            v = Whh[src+e];
    dst[o+e] = f2bf(v);
  }
}
__global__ void pack_l0h_k(const float* __restrict__ Whh0, bf16* __restrict__ dst){
  int tid = blockIdx.x*256 + threadIdx.x;          // 393,216
  int lane = tid & 63;
  int u  = tid >> 6;
  int kk = u & 31;
  int j  = (u >> 5) & 63;
  int g  = u >> 11;
  int row = g*1024 + j*16 + (lane&15);
  int k   = kk*32 + ((lane>>4)&3)*8;
  size_t src = (size_t)row*1024 + k;
  size_t o = (size_t)tid*8;
  #pragma unroll
  for (int e=0;e<8;e++) dst[o+e] = f2bf(Whh0[src+e]);
}
__global__ void pack_l0x_k(const float* __restrict__ Wih0, bf16* __restrict__ dst){
  int tid = blockIdx.x*256 + threadIdx.x;          // 49,152
  int lane = tid & 63;
  int u  = tid >> 6;
  int kk = u & 3;
  int j  = (u >> 2) & 63;
  int g  = u >> 8;
  int row = g*1024 + j*16 + (lane&15);
  int k   = kk*32 + ((lane>>4)&3)*8;
  size_t src = (size_t)row*128 + k;
  size_t o = (size_t)tid*8;
  #pragma unroll
  for (int e=0;e<8;e++) dst[o+e] = f2bf(Wih0[src+e]);
}
__global__ void pack_imp_k(const float* __restrict__ Wp, bf16* __restrict__ dst){
  int tid = blockIdx.x*256 + threadIdx.x;          // 16,384
  int lane = tid & 63;
  int u  = tid >> 6;
  int kk = u & 31;
  int jj = u >> 5;
  int row = jj*16 + (lane&15);
  int k   = kk*32 + ((lane>>4)&3)*8;
  size_t src = (size_t)row*1024 + k;
  size_t o = (size_t)tid*8;
  #pragma unroll
  for (int e=0;e<8;e++) dst[o+e] = f2bf(Wp[src+e]);
}
__global__ void init_pk(u32* __restrict__ bar, bf16* __restrict__ h3,
                        bf16* __restrict__ comp, const float* __restrict__ x){
  int tid = blockIdx.x*256 + threadIdx.x;          // 393,216
  if (tid < 1024) bar[tid] = 0u;
  if (tid < 16384) comp[tid] = f2bf(x[(size_t)(tid>>7)*16384 + (tid&127)]);
  h3[tid] = f2bf(0.f);
}

// =================================================================
// LDS staging of h (32 rows x 1024, fragment order) — validated r5.
// =================================================================
__device__ __forceinline__ void stage_h(const bf16* __restrict__ src_rg, bf16* lds_h,
                                        int wave, int lane){
  const int sh = wave & 1, si = (wave >> 1) & 7;
  const int l15 = lane & 15, quad = lane >> 4;
  const bf16* g = src_rg + (size_t)(sh*16 + l15)*1024 + si*32 + quad*8;
  v4u r0,r1,r2,r3;
  ldx4_coh(g, g+256, g+512, g+768, r0,r1,r2,r3);
  bf16* d = lds_h + ((size_t)wave*64 + lane)*8;
  *(v4u*)(d)         = r0;
  *(v4u*)(d + 8192)  = r1;
  *(v4u*)(d + 16384) = r2;
  *(v4u*)(d + 24576) = r3;
}
__device__ __forceinline__ v8bf afrag(const bf16* lds_h, int kk, int ah, int lane){
  return ldv(lds_h + ((size_t)(kk*2+ah)*64 + lane)*8);
}
__device__ __forceinline__ float hp_lds(const bf16* lds_h, int rl, int colh){
  int kk = colh >> 5, q = (colh >> 3) & 3, e = colh & 7;
  int ah = rl >> 4, lr = rl & 15;
  return bf2f(lds_h[((size_t)(kk*2+ah)*64 + q*16 + lr)*8 + e]);
}

#define MFMA(a,b,c) __builtin_amdgcn_mfma_f32_16x16x32_bf16((a),(b),(c),0,0,0)

// ---- weight prefetch into VGPRs (issued before barrier spin) ----
__device__ __forceinline__ void pf_L0(const bf16* __restrict__ packL0h,
                                      const bf16* __restrict__ packL0x,
                                      int wave, int lane, int jpair, v8bf* w){
  if (wave < 12){
    const int g = wave % 3, jsub = (wave/3) & 1, ksec = wave/6;
    const int j = jpair*2 + jsub;
    const bf16* wp = packL0h + ((size_t)((g*64 + j)*32 + ksec*16))*512 + lane*8;
    #pragma unroll
    for (int i=0;i<16;i++) w[i] = ldv(wp + (size_t)i*512);
  } else if (wave < 15){
    const int g = wave - 12;
    #pragma unroll
    for (int jsub=0;jsub<2;jsub++){
      const bf16* wp = packL0x + ((size_t)((g*64 + jpair*2 + jsub)*4))*512 + lane*8;
      #pragma unroll
      for (int i=0;i<4;i++) w[jsub*4+i] = ldv(wp + (size_t)i*512);
    }
  }
}
__device__ __forceinline__ void pf_U(const bf16* __restrict__ packL,
                                     int wave, int lane, int jpair, v8bf* w){
  const int s = wave & 3, jsub = (wave>>2) & 1, ksec = wave >> 3;
  const int j = jpair*2 + jsub;
  const bf16* wp = packL + ((size_t)((s*64 + j)*32 + ksec*16))*512 + lane*8;
  #pragma unroll
  for (int i=0;i<16;i++) w[i] = ldv(wp + (size_t)i*512);
}
__device__ __forceinline__ void pf_IC(const bf16* __restrict__ packImp,
                                      int wave, int lane, int jj, v8bf* w){
  const bf16* wp = packImp + ((size_t)(jj*32 + wave*2))*512 + lane*8;
  w[0] = ldv(wp);
  w[1] = ldv(wp + 512);
}

// =================================================================
// Main persistent kernel: 128 blocks x 1024 threads (16 waves).
// =================================================================
__global__ __launch_bounds__(1024, 4) void gru_pk(
  const float* __restrict__ x, const float* __restrict__ masks,
  const float* __restrict__ bih0, const float* __restrict__ bhh0,
  const float* __restrict__ bihR, const float* __restrict__ bhhR,
  const float* __restrict__ bp,
  const bf16* __restrict__ packU, const bf16* __restrict__ packL0h,
  const bf16* __restrict__ packL0x, const bf16* __restrict__ packImp,
  bf16* hA, bf16* hB, bf16* hC, bf16* comp,
  u32* bar, float* out)
{
  const int tid  = threadIdx.x;
  const int lane = tid & 63;
  const int wave = tid >> 6;           // 0..15
  const int l15  = lane & 15;
  const int quad = lane >> 4;
  const int bid  = blockIdx.x;
  const int leaf = bid & 7;
  const int up   = bid >> 3;           // 0..15
  const int rg   = up & 3;             // row group
  const int jpair= leaf*4 + (up >> 2); // 0..31
  const int rg32 = rg * 32;
  const bool icblk = ((up >> 2) == 0); // 8 blocks per group, jj = leaf
  u32* ctr = bar + rg*128;
  u32* ep  = bar + rg*128 + 64;

  __shared__ bf16 lds_h[32768];        // 64 KB staged h slice
  __shared__ bf16 lds_c[4096];         // 8 KB staged comp slice
  __shared__ float lds2[18*512];       // 36 KB pre-activation partials
  u32 bc = 0;
  v8bf wreg[16];                       // prefetched weight fragments (64 VGPRs)

  pf_L0(packL0h, packL0x, wave, lane, jpair, wreg);

  #pragma unroll 1
  for (int t = 0; t < 128; ++t){
    // ================= L0: hB = GRU0(input=comp, hidden=hA) =================
    {
      stage_h(hA + (size_t)rg32*1024, lds_h, wave, lane);
      if (wave < 8){
        const int sh = wave & 1, skk = wave >> 1;
        const bf16* g = comp + (size_t)(rg32 + sh*16 + l15)*128 + skk*32 + quad*8;
        v4u r = ldx1_coh(g);
        *(v4u*)(lds_c + ((size_t)wave*64 + lane)*8) = r;
      }
      __syncthreads();
      if (wave < 12){
        const int ksec = wave/6;
        v4f a0 = {0.f,0.f,0.f,0.f}, a1 = {0.f,0.f,0.f,0.f};
        #pragma unroll
        for (int i=0;i<16;++i){
          int kk = ksec*16 + i;
          a0 = MFMA(afrag(lds_h, kk, 0, lane), wreg[i], a0);
          a1 = MFMA(afrag(lds_h, kk, 1, lane), wreg[i], a1);
        }
        #pragma unroll
        for (int r=0;r<4;r++){
          lds2[(wave*32 + quad*4 + r)*16 + l15]      = a0[r];
          lds2[(wave*32 + 16 + quad*4 + r)*16 + l15] = a1[r];
        }
      } else if (wave < 15){
        const int g = wave - 12;
        #pragma unroll
        for (int jsub=0;jsub<2;++jsub){
          v4f a0 = {0.f,0.f,0.f,0.f}, a1 = {0.f,0.f,0.f,0.f};
          #pragma unroll
          for (int i=0;i<4;++i){
            a0 = MFMA(ldv(lds_c + ((size_t)(i*2+0)*64 + lane)*8), wreg[jsub*4+i], a0);
            a1 = MFMA(ldv(lds_c + ((size_t)(i*2+1)*64 + lane)*8), wreg[jsub*4+i], a1);
          }
          const int slot = 12 + g*2 + jsub;
          #pragma unroll
          for (int r=0;r<4;r++){
            lds2[(slot*32 + quad*4 + r)*16 + l15]      = a0[r];
            lds2[(slot*32 + 16 + quad*4 + r)*16 + l15] = a1[r];
          }
        }
      }
      __syncthreads();
      {
        const int rl = tid >> 5, c2 = tid & 31;
        const int jsub = c2 >> 4, c = c2 & 15;
        const int col = jpair*32 + c2;
        float ghr = lds2[((0+jsub*3)*32+rl)*16+c] + lds2[((6+jsub*3)*32+rl)*16+c];
        float ghz = lds2[((1+jsub*3)*32+rl)*16+c] + lds2[((7+jsub*3)*32+rl)*16+c];
        float ghn = lds2[((2+jsub*3)*32+rl)*16+c] + lds2[((8+jsub*3)*32+rl)*16+c];
        float gir = lds2[((12+jsub)*32+rl)*16+c];
        float giz = lds2[((14+jsub)*32+rl)*16+c];
        float gin = lds2[((16+jsub)*32+rl)*16+c];
        float rgg = sigm(gir + bih0[col]      + ghr + bhh0[col]);
        float zg  = sigm(giz + bih0[1024+col] + ghz + bhh0[1024+col]);
        float nv  = tanh_(gin + bih0[2048+col] + rgg*(ghn + bhh0[2048+col]));
        float hp  = hp_lds(lds_h, rl, col);
        st2_coh(hB + (size_t)(rg32+rl)*1024 + col, f2bf((1.f - zg)*nv + zg*hp));
        vdrain();
      }
      pf_U(packU, wave, lane, jpair, wreg);           // prefetch L1 weights
      gbar2(ctr, ep, ++bc);
    }

    // ================= L1 / L2: upper layers =================
    #pragma unroll 1
    for (int lay = 0; lay < 2; ++lay){
      const bf16* src = lay ? hC : hB;
      bf16*       dst = lay ? hA : hC;
      const float* bi = bihR + lay*3072;
      const float* bh = bhhR + lay*3072;
      float* out_h = (lay == 1 && t == 127) ? out : nullptr;

      stage_h(src + (size_t)rg32*1024, lds_h, wave, lane);
      __syncthreads();
      {
        const int ksec = wave >> 3;
        v4f a0 = {0.f,0.f,0.f,0.f}, a1 = {0.f,0.f,0.f,0.f};
        #pragma unroll
        for (int i=0;i<16;++i){
          int kk = ksec*16 + i;
          a0 = MFMA(afrag(lds_h, kk, 0, lane), wreg[i], a0);
          a1 = MFMA(afrag(lds_h, kk, 1, lane), wreg[i], a1);
        }
        #pragma unroll
        for (int r=0;r<4;r++){
          lds2[(wave*32 + quad*4 + r)*16 + l15]      = a0[r];
          lds2[(wave*32 + 16 + quad*4 + r)*16 + l15] = a1[r];
        }
      }
      __syncthreads();
      {
        const int rl = tid >> 5, c2 = tid & 31;
        const int jsub = c2 >> 4, c = c2 & 15;
        const int col = jpair*32 + c2;
        float pr  = lds2[((0+jsub*4)*32+rl)*16+c] + lds2[((8+jsub*4)*32+rl)*16+c];
        float pz  = lds2[((1+jsub*4)*32+rl)*16+c] + lds2[((9+jsub*4)*32+rl)*16+c];
        float pin = lds2[((2+jsub*4)*32+rl)*16+c] + lds2[((10+jsub*4)*32+rl)*16+c];
        float phn = lds2[((3+jsub*4)*32+rl)*16+c] + lds2[((11+jsub*4)*32+rl)*16+c];
        float rgg = sigm(pr + bi[col] + bh[col]);
        float zg  = sigm(pz + bi[1024+col] + bh[1024+col]);
        float nv  = tanh_(pin + bi[2048+col] + rgg*(phn + bh[2048+col]));
        float hp  = hp_lds(lds_h, rl, col);
        float hv  = (1.f - zg)*nv + zg*hp;
        st2_coh(dst + (size_t)(rg32+rl)*1024 + col, f2bf(hv));
        if (out_h) out_h[(size_t)(rg32+rl)*1024 + col] = hv;
        vdrain();
      }
      if (lay == 0){
        pf_U(packU + 4194304, wave, lane, jpair, wreg);   // prefetch L2 weights
      } else if (t != 127){
        if (icblk) pf_IC(packImp, wave, lane, leaf, wreg);
        else       pf_L0(packL0h, packL0x, wave, lane, jpair, wreg);
      }
      gbar2(ctr, ep, ++bc);
    }

    // ================= IC: imputed/completed (t < 127) =================
    if (t != 127){
      if (icblk){
        stage_h(hA + (size_t)rg32*1024, lds_h, wave, lane);
        __syncthreads();
        const int jj = leaf;
        v4f a0 = {0.f,0.f,0.f,0.f}, a1 = {0.f,0.f,0.f,0.f};
        #pragma unroll
        for (int i=0;i<2;++i){
          int kk = wave*2 + i;
          a0 = MFMA(afrag(lds_h, kk, 0, lane), wreg[i], a0);
          a1 = MFMA(afrag(lds_h, kk, 1, lane), wreg[i], a1);
        }
        #pragma unroll
        for (int r=0;r<4;r++){
          lds2[(wave*32 + quad*4 + r)*16 + l15]      = a0[r];
          lds2[(wave*32 + 16 + quad*4 + r)*16 + l15] = a1[r];
        }
        __syncthreads();
        if (tid < 512){
          const int rl = tid >> 4, c = tid & 15;
          const int row = rg32 + rl, d = jj*16 + c;
          float imp = bp[d];
          #pragma unroll
          for (int w2=0; w2<16; ++w2) imp += lds2[(w2*32+rl)*16+c];
          float m  = masks[row*128 + t];
          float xv = x[((size_t)row*128 + t)*128 + d];
          float cv = m*xv + (1.f - m)*imp;
          size_t o = ((size_t)row*127 + t)*128 + d;
          out[131072 + o]  = cv;    // completed
          out[2211840 + o] = imp;   // imputed
          st2_coh(comp + (size_t)row*128 + d, f2bf(cv));
          vdrain();
        }
        pf_L0(packL0h, packL0x, wave, lane, jpair, wreg);  // reload L0 weights
      }
      gbar2(ctr, ep, ++bc);
    }
  }
}

// ---------------- host ----------------
extern "C" void kernel_launch(void* const* d_in, const int* in_sizes, int n_in,
                              void* d_out, int out_size, void* d_ws, size_t ws_size,
                              hipStream_t stream)
{
  (void)in_sizes; (void)n_in; (void)out_size; (void)ws_size;
  const float* x     = (const float*)d_in[0];
  const float* masks = (const float*)d_in[1];
  const float* Wih0  = (const float*)d_in[2];
  const float* Whh0  = (const float*)d_in[3];
  const float* bih0  = (const float*)d_in[4];
  const float* bhh0  = (const float*)d_in[5];
  const float* WihR  = (const float*)d_in[6];
  const float* WhhR  = (const float*)d_in[7];
  const float* bihR  = (const float*)d_in[8];
  const float* bhhR  = (const float*)d_in[9];
  const float* Wp    = (const float*)d_in[10];
  const float* bp    = (const float*)d_in[11];
  float* out = (float*)d_out;

  u32*  bar     = (u32*)d_ws;
  bf16* hA      = (bf16*)((char*)d_ws + 4096);
  bf16* hB      = hA + 131072;
  bf16* hC      = hB + 131072;
  bf16* comp    = hC + 131072;
  bf16* packU   = comp + 16384;        // 8,388,608 elems
  bf16* packL0h = packU + 8388608;     // 3,145,728
  bf16* packL0x = packL0h + 3145728;   // 393,216
  bf16* packImp = packL0x + 393216;    // 131,072

  hipLaunchKernelGGL(init_pk,      dim3(1536), dim3(256), 0, stream, bar, hA, comp, x);
  hipLaunchKernelGGL(pack_upper_k, dim3(4096), dim3(256), 0, stream, WihR, WhhR, packU);
  hipLaunchKernelGGL(pack_l0h_k,   dim3(1536), dim3(256), 0, stream, Whh0, packL0h);
  hipLaunchKernelGGL(pack_l0x_k,   dim3(192),  dim3(256), 0, stream, Wih0, packL0x);
  hipLaunchKernelGGL(pack_imp_k,   dim3(64),   dim3(256), 0, stream, Wp, packImp);
  hipLaunchKernelGGL(gru_pk,       dim3(128),  dim3(1024), 0, stream,
      x, masks, bih0, bhh0, bihR, bhhR, bp,
      packU, packL0h, packL0x, packImp, hA, hB, hC, comp, bar, out);
}

// Round 7
// 5539.694 us; speedup vs baseline: 1.5365x; 1.5365x over previous
//
#include <hip/hip_runtime.h>
#include <hip/hip_bf16.h>

// GRU-imputation scan (B=128,T=128,D=128,H=1024,L=3), f32 in/out.
// Round 7: r5 base (NO register-array prefetch — r6's array spilled to
// scratch: WRITE_SIZE 4.5GB) + two latency cuts:
//  (1) leaderless monotonic flag barrier (store own flag, poll all 32 via
//      wave-0 lanes + ballot): ~1 LLC RT vs ~2 RT + 2 polls for the tree.
//  (2) IC phase fused into L0: imp/comp computed block-locally from the
//      already-staged hA slice (4 -> 3 barriers/step, comp buffer gone).
// 4 row groups x 32 blocks, sc0/sc1-coherent h, bf16-packed L2-resident
// weights (r/z pre-summed for upper layers).

typedef __hip_bfloat16 bf16;
typedef unsigned int u32;
typedef unsigned short u16;
typedef __attribute__((ext_vector_type(8))) short v8bf;   // 8 x bf16 (16B)
typedef __attribute__((ext_vector_type(4))) float v4f;    // MFMA C/D
typedef __attribute__((ext_vector_type(4))) u32 v4u;

#define SC __HIP_MEMORY_SCOPE_AGENT

__device__ __forceinline__ float bf2f(bf16 v){ return __bfloat162float(v); }
__device__ __forceinline__ bf16 f2bf(float v){ return __float2bfloat16(v); }
__device__ __forceinline__ float sigm(float x){ return 1.f/(1.f + __expf(-x)); }
__device__ __forceinline__ float tanh_(float x){
  float a = fminf(fmaxf(x, -15.f), 15.f);
  float t = __expf(2.f*a);
  return (t-1.f)/(t+1.f);
}
__device__ __forceinline__ v8bf ldv(const bf16* p){ return *reinterpret_cast<const v8bf*>(p); }
__device__ __forceinline__ void vdrain(){ asm volatile("s_waitcnt vmcnt(0)" ::: "memory"); }

// f32x8 (cached) -> bf16 fragment
__device__ __forceinline__ v8bf cvt8f(const float* p){
  const v4u a = *reinterpret_cast<const v4u*>(p);
  const v4u b = *reinterpret_cast<const v4u*>(p + 4);
  v8bf r;
  #pragma unroll
  for (int i=0;i<4;i++){ r[i]   = (short)(a[i] >> 16); }
  #pragma unroll
  for (int i=0;i<4;i++){ r[4+i] = (short)(b[i] >> 16); }
  return r;
}

// ---- device-coherent (LLC) accesses: bypass L1+L2 via sc0 sc1 ----
__device__ __forceinline__ void ldx4_coh(const bf16* p0, const bf16* p1,
                                         const bf16* p2, const bf16* p3,
                                         v4u& r0, v4u& r1, v4u& r2, v4u& r3){
  asm volatile(
    "global_load_dwordx4 %0, %4, off sc0 sc1\n\t"
    "global_load_dwordx4 %1, %5, off sc0 sc1\n\t"
    "global_load_dwordx4 %2, %6, off sc0 sc1\n\t"
    "global_load_dwordx4 %3, %7, off sc0 sc1\n\t"
    "s_waitcnt vmcnt(0)"
    : "=&v"(r0), "=&v"(r1), "=&v"(r2), "=&v"(r3)
    : "v"(p0), "v"(p1), "v"(p2), "v"(p3)
    : "memory");
}
__device__ __forceinline__ void st2_coh(bf16* p, bf16 v){
  u32 vv = (u32)__builtin_bit_cast(u16, v);
  asm volatile("global_store_short %0, %1, off sc0 sc1" :: "v"(p), "v"(vv) : "memory");
}
__device__ __forceinline__ u32 ld_flag(const u32* p){
  u32 r;
  asm volatile("global_load_dword %0, %1, off sc0 sc1\n\ts_waitcnt vmcnt(0)"
               : "=v"(r) : "v"(p) : "memory");
  return r;
}
__device__ __forceinline__ void st_flag(u32* p, u32 v){
  asm volatile("global_store_dword %0, %1, off sc0 sc1" :: "v"(p), "v"(v) : "memory");
}

// ---- leaderless flag barrier: 32 slots x 128B, monotonic epochs ----
// fl = group flag base (1024 u32). slot = this block's slot (0..31).
__device__ __forceinline__ void fbar(u32* fl, int slot, u32 target){
  __syncthreads();
  const int tid = threadIdx.x;
  if (tid == 0){ vdrain(); st_flag(fl + slot*32, target); }
  if (tid < 64){
    const bool act = tid < 32;
    const u32* p = fl + (tid & 31)*32;
    while (true){
      u32 v = act ? ld_flag(p) : 0u;
      unsigned long long ok = __ballot(!act || v >= target);
      if (ok == ~0ull) break;
      __builtin_amdgcn_s_sleep(1);
    }
  }
  __syncthreads();
}

// =================================================================
// Packing kernels (validated r4-r6). Fragment unit = 64 lanes x 8 bf16:
//   lane's 8 elems = W[row(j,lane&15)][kk*32 + ((lane>>4)&3)*8 + e]
// =================================================================
__global__ void pack_upper_k(const float* __restrict__ Wih, const float* __restrict__ Whh,
                             bf16* __restrict__ dst){
  int tid = blockIdx.x*256 + threadIdx.x;          // 1,048,576
  int lane = tid & 63;
  int u    = tid >> 6;
  int kk   = u & 31;
  int j    = (u >> 5) & 63;
  int s    = (u >> 11) & 3;
  int l    = u >> 13;
  int n    = j*16 + (lane & 15);
  int k    = kk*32 + ((lane>>4)&3)*8;
  int row  = (s==0) ? n : (s==1 ? 1024+n : 2048+n);
  size_t src = ((size_t)l*3072 + row)*1024 + k;
  size_t o = (size_t)tid*8;
  #pragma unroll
  for (int e=0;e<8;e++){
    float v;
    if (s < 2)      v = Wih[src+e] + Whh[src+e];
    else if (s==2)  v = Wih[src+e];
    else            v = Whh[src+e];
    dst[o+e] = f2bf(v);
  }
}
__global__ void pack_l0h_k(const float* __restrict__ Whh0, bf16* __restrict__ dst){
  int tid = blockIdx.x*256 + threadIdx.x;          // 393,216
  int lane = tid & 63;
  int u  = tid >> 6;
  int kk = u & 31;
  int j  = (u >> 5) & 63;
  int g  = u >> 11;
  int row = g*1024 + j*16 + (lane&15);
  int k   = kk*32 + ((lane>>4)&3)*8;
  size_t src = (size_t)row*1024 + k;
  size_t o = (size_t)tid*8;
  #pragma unroll
  for (int e=0;e<8;e++) dst[o+e] = f2bf(Whh0[src+e]);
}
__global__ void pack_l0x_k(const float* __restrict__ Wih0, bf16* __restrict__ dst){
  int tid = blockIdx.x*256 + threadIdx.x;          // 49,152
  int lane = tid & 63;
  int u  = tid >> 6;
  int kk = u & 3;
  int j  = (u >> 2) & 63;
  int g  = u >> 8;
  int row = g*1024 + j*16 + (lane&15);
  int k   = kk*32 + ((lane>>4)&3)*8;
  size_t src = (size_t)row*128 + k;
  size_t o = (size_t)tid*8;
  #pragma unroll
  for (int e=0;e<8;e++) dst[o+e] = f2bf(Wih0[src+e]);
}
__global__ void pack_imp_k(const float* __restrict__ Wp, bf16* __restrict__ dst){
  int tid = blockIdx.x*256 + threadIdx.x;          // 16,384
  int lane = tid & 63;
  int u  = tid >> 6;
  int kk = u & 31;
  int jj = u >> 5;
  int row = jj*16 + (lane&15);
  int k   = kk*32 + ((lane>>4)&3)*8;
  size_t src = (size_t)row*1024 + k;
  size_t o = (size_t)tid*8;
  #pragma unroll
  for (int e=0;e<8;e++) dst[o+e] = f2bf(Wp[src+e]);
}
// init: flags[4096]=0, h3 (hA|hB|hC) = 0
__global__ void init_pk(u32* __restrict__ bar, bf16* __restrict__ h3){
  int tid = blockIdx.x*256 + threadIdx.x;          // 393,216
  if (tid < 4096) bar[tid] = 0u;
  h3[tid] = f2bf(0.f);
}

// =================================================================
// LDS staging of h (32 rows x 1024, fragment order) — validated r5.
// unit = kk*2 + half; chunk-in-unit = lane; elem = h[half*16+l15][kk*32+quad*8+e]
// =================================================================
__device__ __forceinline__ void stage_h(const bf16* __restrict__ src_rg, bf16* lds_h,
                                        int wave, int lane){
  const int sh = wave & 1, si = (wave >> 1) & 7;
  const int l15 = lane & 15, quad = lane >> 4;
  const bf16* g = src_rg + (size_t)(sh*16 + l15)*1024 + si*32 + quad*8;
  v4u r0,r1,r2,r3;
  ldx4_coh(g, g+256, g+512, g+768, r0,r1,r2,r3);
  bf16* d = lds_h + ((size_t)wave*64 + lane)*8;
  *(v4u*)(d)         = r0;
  *(v4u*)(d + 8192)  = r1;
  *(v4u*)(d + 16384) = r2;
  *(v4u*)(d + 24576) = r3;
}
__device__ __forceinline__ v8bf afrag(const bf16* lds_h, int kk, int ah, int lane){
  return ldv(lds_h + ((size_t)(kk*2+ah)*64 + lane)*8);
}
__device__ __forceinline__ float hp_lds(const bf16* lds_h, int rl, int colh){
  int kk = colh >> 5, q = (colh >> 3) & 3, e = colh & 7;
  int ah = rl >> 4, lr = rl & 15;
  return bf2f(lds_h[((size_t)(kk*2+ah)*64 + q*16 + lr)*8 + e]);
}

#define MFMA(a,b,c) __builtin_amdgcn_mfma_f32_16x16x32_bf16((a),(b),(c),0,0,0)

// =================================================================
// Main persistent kernel: 128 blocks x 1024 threads (16 waves).
// leaf=bid&7 (XCD weight affinity), up=bid>>3, rg=up&3 (row group, 32 rows),
// jpair=leaf*4+(up>>2) (32 output cols). slot-in-group = (up>>2)*8+leaf.
// =================================================================
__global__ __launch_bounds__(1024, 4) void gru_pk(
  const float* __restrict__ x, const float* __restrict__ masks,
  const float* __restrict__ bih0, const float* __restrict__ bhh0,
  const float* __restrict__ bihR, const float* __restrict__ bhhR,
  const float* __restrict__ bp,
  const bf16* __restrict__ packU, const bf16* __restrict__ packL0h,
  const bf16* __restrict__ packL0x, const bf16* __restrict__ packImp,
  bf16* hA, bf16* hB, bf16* hC,
  u32* bar, float* out)
{
  const int tid  = threadIdx.x;
  const int lane = tid & 63;
  const int wave = tid >> 6;           // 0..15
  const int l15  = lane & 15;
  const int quad = lane >> 4;
  const int bid  = blockIdx.x;
  const int leaf = bid & 7;
  const int up   = bid >> 3;           // 0..15
  const int rg   = up & 3;
  const int jpair= leaf*4 + (up >> 2); // 0..31
  const int rg32 = rg * 32;
  const int slot = (up >> 2)*8 + leaf; // 0..31 within group
  const bool wr  = (up >> 2) == 0;     // designated out-writer (d slice = leaf)
  u32* fl = bar + rg*1024;

  __shared__ bf16 lds_h[32768];        // 64 KB staged h slice
  __shared__ bf16 lds_c[4096];         // 8 KB comp (A-frag layout)
  __shared__ float lds2[18*512];       // 36 KB pre-activation partials
  __shared__ float lds_i[4096];        // 16 KB imp [row][d]
  u32 bc = 0;

  #pragma unroll 1
  for (int t = 0; t < 128; ++t){
    // ========== Phase A: fused imp/comp(t-1) + L0 -> hB ==========
    {
      stage_h(hA + (size_t)rg32*1024, lds_h, wave, lane);
      __syncthreads();
      if (t == 0){
        // comp(-1) = x[:,0,:]
        if (wave < 8){
          const int sh = wave & 1, skk = wave >> 1;
          const float* g = x + (size_t)(rg32 + sh*16 + l15)*16384 + skk*32 + quad*8;
          *(v8bf*)(lds_c + ((size_t)wave*64 + lane)*8) = cvt8f(g);
        }
      } else {
        // imp(t-1) = hA @ Wp^T + bp, locally (all 16 waves, full K)
        const int jj = wave & 7, ah = wave >> 3;
        v4f acc = {0.f,0.f,0.f,0.f};
        const bf16* wp = packImp + ((size_t)jj*32)*512 + lane*8;
        #pragma unroll
        for (int kk=0; kk<32; ++kk)
          acc = MFMA(afrag(lds_h, kk, ah, lane), ldv(wp + (size_t)kk*512), acc);
        #pragma unroll
        for (int r=0;r<4;r++){
          const int rl = ah*16 + quad*4 + r;
          const int d  = jj*16 + l15;
          float imp = acc[r] + bp[d];
          lds_i[rl*128 + d] = imp;
          float m  = masks[(size_t)(rg32+rl)*128 + (t-1)];
          float xv = x[((size_t)(rg32+rl)*128 + (t-1))*128 + d];
          float cv = m*xv + (1.f-m)*imp;
          const int chunk = d>>5, qq = (d>>3)&3, e = d&7, lr = quad*4+r;
          lds_c[((size_t)(chunk*2+ah)*64 + qq*16 + lr)*8 + e] = f2bf(cv);
        }
      }
      __syncthreads();
      // designated blocks write imputed/completed for step t-1
      if (t > 0 && wr && tid < 512){
        const int rl = tid >> 4, c = tid & 15;
        const int d = leaf*16 + c;
        float imp = lds_i[rl*128 + d];
        float m  = masks[(size_t)(rg32+rl)*128 + (t-1)];
        float xv = x[((size_t)(rg32+rl)*128 + (t-1))*128 + d];
        float cv = m*xv + (1.f-m)*imp;
        size_t o = ((size_t)(rg32+rl)*127 + (t-1))*128 + d;
        out[131072 + o]  = cv;    // completed
        out[2211840 + o] = imp;   // imputed
      }
      // L0 GEMMs
      if (wave < 12){
        const int g = wave % 3, jsub = (wave/3) & 1, ksec = wave/6;
        const int j = jpair*2 + jsub;
        v4f a0 = {0.f,0.f,0.f,0.f}, a1 = {0.f,0.f,0.f,0.f};
        const bf16* wp = packL0h + ((size_t)((g*64 + j)*32 + ksec*16))*512 + lane*8;
        #pragma unroll
        for (int i=0;i<16;++i){
          int kk = ksec*16 + i;
          v8bf wf = ldv(wp + (size_t)i*512);
          a0 = MFMA(afrag(lds_h, kk, 0, lane), wf, a0);
          a1 = MFMA(afrag(lds_h, kk, 1, lane), wf, a1);
        }
        #pragma unroll
        for (int r=0;r<4;r++){
          lds2[(wave*32 + quad*4 + r)*16 + l15]      = a0[r];
          lds2[(wave*32 + 16 + quad*4 + r)*16 + l15] = a1[r];
        }
      } else if (wave < 15){
        const int g = wave - 12;
        #pragma unroll
        for (int jsub=0;jsub<2;++jsub){
          const int j = jpair*2 + jsub;
          v4f a0 = {0.f,0.f,0.f,0.f}, a1 = {0.f,0.f,0.f,0.f};
          const bf16* wp = packL0x + ((size_t)((g*64 + j)*4))*512 + lane*8;
          #pragma unroll
          for (int i=0;i<4;++i){
            v8bf wf = ldv(wp + (size_t)i*512);
            a0 = MFMA(ldv(lds_c + ((size_t)(i*2+0)*64 + lane)*8), wf, a0);
            a1 = MFMA(ldv(lds_c + ((size_t)(i*2+1)*64 + lane)*8), wf, a1);
          }
          const int sl = 12 + g*2 + jsub;
          #pragma unroll
          for (int r=0;r<4;r++){
            lds2[(sl*32 + quad*4 + r)*16 + l15]      = a0[r];
            lds2[(sl*32 + 16 + quad*4 + r)*16 + l15] = a1[r];
          }
        }
      }
      __syncthreads();
      {
        const int rl = tid >> 5, c2 = tid & 31;
        const int jsub = c2 >> 4, c = c2 & 15;
        const int col = jpair*32 + c2;
        float ghr = lds2[((0+jsub*3)*32+rl)*16+c] + lds2[((6+jsub*3)*32+rl)*16+c];
        float ghz = lds2[((1+jsub*3)*32+rl)*16+c] + lds2[((7+jsub*3)*32+rl)*16+c];
        float ghn = lds2[((2+jsub*3)*32+rl)*16+c] + lds2[((8+jsub*3)*32+rl)*16+c];
        float gir = lds2[((12+jsub)*32+rl)*16+c];
        float giz = lds2[((14+jsub)*32+rl)*16+c];
        float gin = lds2[((16+jsub)*32+rl)*16+c];
        float rgg = sigm(gir + bih0[col]      + ghr + bhh0[col]);
        float zg  = sigm(giz + bih0[1024+col] + ghz + bhh0[1024+col]);
        float nv  = tanh_(gin + bih0[2048+col] + rgg*(ghn + bhh0[2048+col]));
        float hp  = hp_lds(lds_h, rl, col);
        st2_coh(hB + (size_t)(rg32+rl)*1024 + col, f2bf((1.f - zg)*nv + zg*hp));
        vdrain();
      }
      fbar(fl, slot, ++bc);
    }

    // ========== L1 / L2: upper layers ==========
    #pragma unroll 1
    for (int lay = 0; lay < 2; ++lay){
      const bf16* src = lay ? hC : hB;
      bf16*       dst = lay ? hA : hC;
      const bf16* packL = packU + (size_t)lay*4194304;
      const float* bi = bihR + lay*3072;
      const float* bh = bhhR + lay*3072;
      float* out_h = (lay == 1 && t == 127) ? out : nullptr;

      stage_h(src + (size_t)rg32*1024, lds_h, wave, lane);
      __syncthreads();
      {
        const int s = wave & 3, jsub = (wave>>2) & 1, ksec = wave >> 3;
        const int j = jpair*2 + jsub;
        v4f a0 = {0.f,0.f,0.f,0.f}, a1 = {0.f,0.f,0.f,0.f};
        const bf16* wp = packL + ((size_t)((s*64 + j)*32 + ksec*16))*512 + lane*8;
        #pragma unroll
        for (int i=0;i<16;++i){
          int kk = ksec*16 + i;
          v8bf wf = ldv(wp + (size_t)i*512);
          a0 = MFMA(afrag(lds_h, kk, 0, lane), wf, a0);
          a1 = MFMA(afrag(lds_h, kk, 1, lane), wf, a1);
        }
        #pragma unroll
        for (int r=0;r<4;r++){
          lds2[(wave*32 + quad*4 + r)*16 + l15]      = a0[r];
          lds2[(wave*32 + 16 + quad*4 + r)*16 + l15] = a1[r];
        }
      }
      __syncthreads();
      {
        const int rl = tid >> 5, c2 = tid & 31;
        const int jsub = c2 >> 4, c = c2 & 15;
        const int col = jpair*32 + c2;
        float pr  = lds2[((0+jsub*4)*32+rl)*16+c] + lds2[((8+jsub*4)*32+rl)*16+c];
        float pz  = lds2[((1+jsub*4)*32+rl)*16+c] + lds2[((9+jsub*4)*32+rl)*16+c];
        float pin = lds2[((2+jsub*4)*32+rl)*16+c] + lds2[((10+jsub*4)*32+rl)*16+c];
        float phn = lds2[((3+jsub*4)*32+rl)*16+c] + lds2[((11+jsub*4)*32+rl)*16+c];
        float rgg = sigm(pr + bi[col] + bh[col]);
        float zg  = sigm(pz + bi[1024+col] + bh[1024+col]);
        float nv  = tanh_(pin + bi[2048+col] + rgg*(phn + bh[2048+col]));
        float hp  = hp_lds(lds_h, rl, col);
        float hv  = (1.f - zg)*nv + zg*hp;
        st2_coh(dst + (size_t)(rg32+rl)*1024 + col, f2bf(hv));
        if (out_h) out_h[(size_t)(rg32+rl)*1024 + col] = hv;
        vdrain();
      }
      fbar(fl, slot, ++bc);
    }
  }
}

// ---------------- host ----------------
extern "C" void kernel_launch(void* const* d_in, const int* in_sizes, int n_in,
                              void* d_out, int out_size, void* d_ws, size_t ws_size,
                              hipStream_t stream)
{
  (void)in_sizes; (void)n_in; (void)out_size; (void)ws_size;
  const float* x     = (const float*)d_in[0];
  const float* masks = (const float*)d_in[1];
  const float* Wih0  = (const float*)d_in[2];
  const float* Whh0  = (const float*)d_in[3];
  const float* bih0  = (const float*)d_in[4];
  const float* bhh0  = (const float*)d_in[5];
  const float* WihR  = (const float*)d_in[6];
  const float* WhhR  = (const float*)d_in[7];
  const float* bihR  = (const float*)d_in[8];
  const float* bhhR  = (const float*)d_in[9];
  const float* Wp    = (const float*)d_in[10];
  const float* bp    = (const float*)d_in[11];
  float* out = (float*)d_out;

  // ws: flags u32[4096] (16KB) | hA hB hC (bf16 131072 ea) | packed weights
  u32*  bar     = (u32*)d_ws;
  bf16* hA      = (bf16*)((char*)d_ws + 16384);
  bf16* hB      = hA + 131072;
  bf16* hC      = hB + 131072;
  bf16* packU   = hC + 131072;         // 8,388,608 elems
  bf16* packL0h = packU + 8388608;     // 3,145,728
  bf16* packL0x = packL0h + 3145728;   // 393,216
  bf16* packImp = packL0x + 393216;    // 131,072

  hipLaunchKernelGGL(init_pk,      dim3(1536), dim3(256), 0, stream, bar, hA);
  hipLaunchKernelGGL(pack_upper_k, dim3(4096), dim3(256), 0, stream, WihR, WhhR, packU);
  hipLaunchKernelGGL(pack_l0h_k,   dim3(1536), dim3(256), 0, stream, Whh0, packL0h);
  hipLaunchKernelGGL(pack_l0x_k,   dim3(192),  dim3(256), 0, stream, Wih0, packL0x);
  hipLaunchKernelGGL(pack_imp_k,   dim3(64),   dim3(256), 0, stream, Wp, packImp);
  hipLaunchKernelGGL(gru_pk,       dim3(128),  dim3(1024), 0, stream,
      x, masks, bih0, bhh0, bihR, bhhR, bp,
      packU, packL0h, packL0x, packImp, hA, hB, hC, bar, out);
}